// Round 6
// baseline (2020.654 us; speedup 1.0000x reference)
//
#include <hip/hip_runtime.h>
#include <math.h>

#define NN 100000
#define NE 1600000
#define DF 256
#define HH 64
#define TT 4
#define GG 8
#define BN_EPS 1e-5f

#define SCAN_BLK 1024
#define NB_SCAN ((NN + SCAN_BLK - 1) / SCAN_BLK)   // 98

typedef __attribute__((ext_vector_type(8))) short short8v;
typedef __attribute__((ext_vector_type(4))) float f32x4;
typedef unsigned short ushort_t;
typedef unsigned int uint_t;

__device__ __forceinline__ void atomicMaxF(float* addr, float val) {
  if (val >= 0.f) atomicMax((int*)addr, __float_as_int(val));
  else            atomicMin((unsigned int*)addr, __float_as_uint(val));
}

// fp32 -> bf16 bits, round-to-nearest-even
__device__ __forceinline__ short f2bf(float f) {
  uint_t u = __float_as_uint(f);
  u += 0x7FFFu + ((u >> 16) & 1u);
  return (short)(u >> 16);
}
// bf16 pair unpack from uint
__device__ __forceinline__ float bflo(uint_t u) { return __uint_as_float(u << 16); }
__device__ __forceinline__ float bfhi(uint_t u) { return __uint_as_float(u & 0xFFFF0000u); }

// ---------------- init: stats=0, max buffers=-inf ----------------
__global__ void k_init(float* __restrict__ stats, float* __restrict__ maxb) {
  int i = threadIdx.x;
  if (i < 512) stats[i] = 0.f;
  if (i < 64)  maxb[i]  = -INFINITY;
}

// ---------------- prep: fp32 -> bf16 bits ----------------
__global__ void k_prep(const float* __restrict__ W, ushort_t* __restrict__ Wbf, int n) {
  int i = blockIdx.x * 256 + threadIdx.x;
  if (i < n) Wbf[i] = (ushort_t)f2bf(W[i]);
}

// ---------------- GEMM1 (MFMA bf16): h1 = x @ W_first + b, + BN stats ----------------
__global__ __launch_bounds__(256, 2) void k_gemm1_mfma(
    const float* __restrict__ x, const ushort_t* __restrict__ Wbf,
    const float* __restrict__ b, float* __restrict__ h1,
    float* __restrict__ stats) {
  const int lane = threadIdx.x & 63;
  const int li = lane & 15;
  const int lh = lane >> 4;
  const int gw = (blockIdx.x * 256 + (int)threadIdx.x) >> 6;
  const int nw = (gridDim.x * 256) >> 6;

  short8v bf[8][4];
#pragma unroll
  for (int s = 0; s < 8; ++s)
#pragma unroll
    for (int ct = 0; ct < 4; ++ct)
#pragma unroll
      for (int e = 0; e < 8; ++e)
        bf[s][ct][e] = (short)Wbf[(32 * s + 8 * lh + e) * HH + ct * 16 + li];

  float bias[4];
#pragma unroll
  for (int ct = 0; ct < 4; ++ct) bias[ct] = b[ct * 16 + li];

  float ps[4] = {0.f, 0.f, 0.f, 0.f}, pss[4] = {0.f, 0.f, 0.f, 0.f};

  for (int t = gw; t < NN / 16; t += nw) {
    const float* xb = x + (size_t)(t * 16 + li) * DF + 8 * lh;
    f32x4 acc[4];
#pragma unroll
    for (int ct = 0; ct < 4; ++ct) acc[ct] = (f32x4){0.f, 0.f, 0.f, 0.f};

#pragma unroll
    for (int s = 0; s < 8; ++s) {
      float4 a0 = *(const float4*)(xb + 32 * s);
      float4 a1 = *(const float4*)(xb + 32 * s + 4);
      short8v af;
      af[0] = f2bf(a0.x); af[1] = f2bf(a0.y); af[2] = f2bf(a0.z); af[3] = f2bf(a0.w);
      af[4] = f2bf(a1.x); af[5] = f2bf(a1.y); af[6] = f2bf(a1.z); af[7] = f2bf(a1.w);
#pragma unroll
      for (int ct = 0; ct < 4; ++ct)
        acc[ct] = __builtin_amdgcn_mfma_f32_16x16x32_bf16(af, bf[s][ct], acc[ct], 0, 0, 0);
    }

    float* hb = h1 + (size_t)t * 16 * HH;
#pragma unroll
    for (int ct = 0; ct < 4; ++ct) {
#pragma unroll
      for (int r = 0; r < 4; ++r) {
        float h = acc[ct][r] + bias[ct];
        hb[(lh * 4 + r) * HH + ct * 16 + li] = h;
        ps[ct] += h; pss[ct] += h * h;
      }
    }
  }

#pragma unroll
  for (int ct = 0; ct < 4; ++ct) {
    ps[ct]  += __shfl_xor(ps[ct], 16);  ps[ct]  += __shfl_xor(ps[ct], 32);
    pss[ct] += __shfl_xor(pss[ct], 16); pss[ct] += __shfl_xor(pss[ct], 32);
  }
  if (lane < 16) {
#pragma unroll
    for (int ct = 0; ct < 4; ++ct) {
      atomicAdd(&stats[ct * 16 + lane], ps[ct]);
      atomicAdd(&stats[HH + ct * 16 + lane], pss[ct]);
    }
  }
}

// ---------------- BN finalize ----------------
__global__ void k_finalize_bn(const float* __restrict__ sums,
                              const float* __restrict__ gamma,
                              const float* __restrict__ beta,
                              float* __restrict__ ab) {
  int c = threadIdx.x;                                // 64 threads
  float mu  = sums[c] * (1.f / NN);
  float var = sums[HH + c] * (1.f / NN) - mu * mu;
  float a = gamma[c] * rsqrtf(var + BN_EPS);
  ab[c] = a;
  ab[HH + c] = beta[c] - mu * a;
}

// ---------------- normalize+ReLU + head (64->4) + graph max-pool ----------------
// WRITEF: emit f as bf16 (layer 0). ADDOUT: accumulate node_pred (layer 1).
template <int WRITEF, int ADDOUT>
__global__ __launch_bounds__(256) void k_norm_np(
    const float* __restrict__ hin, ushort_t* __restrict__ fout,
    const float* __restrict__ ab, const float* __restrict__ Wlin,
    const float* __restrict__ blin, const int* __restrict__ batch,
    float* __restrict__ node_pred, float* __restrict__ maxbuf, int rpb) {
  __shared__ float lmax[GG * TT];
  if (threadIdx.x < GG * TT) lmax[threadIdx.x] = -INFINITY;
  __syncthreads();

  const int lane = threadIdx.x & 63;
  const int wid  = threadIdx.x >> 6;
  const float a  = ab[lane];
  const float b2 = ab[HH + lane];
  const float4 w = ((const float4*)Wlin)[lane];       // W[lane][0..3]
  const float4 bl = *(const float4*)blin;
  int r0 = blockIdx.x * rpb;
  int r1 = min(r0 + rpb, NN);

  for (int r = r0 + wid; r < r1; r += 4) {
    float h = hin[(size_t)r * HH + lane];
    float f = fmaxf(fmaf(a, h, b2), 0.f);
    if (WRITEF) fout[(size_t)r * HH + lane] = (ushort_t)f2bf(f);
    float p0 = f * w.x, p1 = f * w.y, p2 = f * w.z, p3 = f * w.w;
#pragma unroll
    for (int off = 32; off; off >>= 1) {
      p0 += __shfl_xor(p0, off);
      p1 += __shfl_xor(p1, off);
      p2 += __shfl_xor(p2, off);
      p3 += __shfl_xor(p3, off);
    }
    if (lane == 0) {
      float4 np;
      np.x = p0 + bl.x; np.y = p1 + bl.y; np.z = p2 + bl.z; np.w = p3 + bl.w;
      int g = batch[r];
      atomicMaxF(&lmax[g * TT + 0], np.x);
      atomicMaxF(&lmax[g * TT + 1], np.y);
      atomicMaxF(&lmax[g * TT + 2], np.z);
      atomicMaxF(&lmax[g * TT + 3], np.w);
      float4* op = (float4*)(node_pred + (size_t)r * TT);
      if (ADDOUT) {
        float4 o = *op;
        np.x += o.x; np.y += o.y; np.z += o.z; np.w += o.w;
      }
      *op = np;
    }
  }
  __syncthreads();
  if (threadIdx.x < GG * TT) atomicMaxF(&maxbuf[threadIdx.x], lmax[threadIdx.x]);
}

// ---------------- CSR build: histogram ----------------
__global__ __launch_bounds__(256) void k_count(const int* __restrict__ ei,
                                               int* __restrict__ deg) {
  int i = blockIdx.x * blockDim.x + threadIdx.x;
  int n = gridDim.x * blockDim.x;
  for (int e = i; e < NE; e += n) atomicAdd(&deg[ei[NE + e]], 1);
}

// ---------------- CSR build: 3-kernel exclusive scan ----------------
__global__ __launch_bounds__(256) void k_scanA(const int* __restrict__ deg,
                                               int* __restrict__ rowstart,
                                               int* __restrict__ bsum) {
  __shared__ int s[256];
  int t = threadIdx.x;
  int base = blockIdx.x * SCAN_BLK + t * 4;
  int d0 = 0, d1 = 0, d2 = 0, d3 = 0;
  if (base + 3 < NN) {
    int4 v = *(const int4*)(deg + base);
    d0 = v.x; d1 = v.y; d2 = v.z; d3 = v.w;
  } else {
    if (base + 0 < NN) d0 = deg[base + 0];
    if (base + 1 < NN) d1 = deg[base + 1];
    if (base + 2 < NN) d2 = deg[base + 2];
    if (base + 3 < NN) d3 = deg[base + 3];
  }
  int ts = d0 + d1 + d2 + d3;
  s[t] = ts;
  __syncthreads();
  for (int off = 1; off < 256; off <<= 1) {
    int v = (t >= off) ? s[t - off] : 0;
    __syncthreads();
    s[t] += v;
    __syncthreads();
  }
  int excl = s[t] - ts;                  // block-local exclusive prefix
  if (base + 0 < NN) rowstart[base + 0] = excl;  excl += d0;
  if (base + 1 < NN) rowstart[base + 1] = excl;  excl += d1;
  if (base + 2 < NN) rowstart[base + 2] = excl;  excl += d2;
  if (base + 3 < NN) rowstart[base + 3] = excl;
  if (t == 255) bsum[blockIdx.x] = s[255];
}

__global__ void k_scanB(const int* __restrict__ bsum, int* __restrict__ bscan) {
  __shared__ int s[128];
  int t = threadIdx.x;                   // 128 threads
  int v = (t < NB_SCAN) ? bsum[t] : 0;
  s[t] = v;
  __syncthreads();
  for (int off = 1; off < 128; off <<= 1) {
    int u = (t >= off) ? s[t - off] : 0;
    __syncthreads();
    s[t] += u;
    __syncthreads();
  }
  if (t < NB_SCAN) bscan[t] = s[t] - v;
}

__global__ __launch_bounds__(256) void k_scanC(int* __restrict__ rowstart,
                                               const int* __restrict__ bscan,
                                               int* __restrict__ cursor) {
  int off = bscan[blockIdx.x];
  int base = blockIdx.x * SCAN_BLK + threadIdx.x * 4;
#pragma unroll
  for (int j = 0; j < 4; ++j) {
    int i = base + j;
    if (i < NN) {
      int r = rowstart[i] + off;
      rowstart[i] = r;
      cursor[i] = r;
    }
  }
}

// ---------------- CSR build: fill src lists ----------------
__global__ __launch_bounds__(256) void k_fill(const int* __restrict__ ei,
                                              int* __restrict__ cursor,
                                              int* __restrict__ srcl) {
  int i = blockIdx.x * blockDim.x + threadIdx.x;
  int n = gridDim.x * blockDim.x;
  for (int e = i; e < NE; e += n) {
    int src = ei[e];
    int dst = ei[NE + e];
    int p = atomicAdd(&cursor[dst], 1);
    srcl[p] = src;
  }
}

// ---------------- GEMM2 (MFMA bf16): g = f @ W_conv (no bias), bf16 out ----------------
__global__ __launch_bounds__(256) void k_gemm2_mfma(
    const ushort_t* __restrict__ fbf, const ushort_t* __restrict__ Wbf2,
    ushort_t* __restrict__ g) {
  const int lane = threadIdx.x & 63;
  const int li = lane & 15;
  const int lh = lane >> 4;
  const int gw = (blockIdx.x * 256 + (int)threadIdx.x) >> 6;
  const int nw = (gridDim.x * 256) >> 6;

  short8v bfr[2][4];
#pragma unroll
  for (int s = 0; s < 2; ++s)
#pragma unroll
    for (int ct = 0; ct < 4; ++ct)
#pragma unroll
      for (int e = 0; e < 8; ++e)
        bfr[s][ct][e] = (short)Wbf2[(32 * s + 8 * lh + e) * HH + ct * 16 + li];

  for (int t = gw; t < NN / 16; t += nw) {
    const ushort_t* fb = fbf + (size_t)(t * 16 + li) * HH + 8 * lh;
    short8v a0 = *(const short8v*)(fb);
    short8v a1 = *(const short8v*)(fb + 32);
    f32x4 acc[4];
#pragma unroll
    for (int ct = 0; ct < 4; ++ct) {
      acc[ct] = (f32x4){0.f, 0.f, 0.f, 0.f};
      acc[ct] = __builtin_amdgcn_mfma_f32_16x16x32_bf16(a0, bfr[0][ct], acc[ct], 0, 0, 0);
      acc[ct] = __builtin_amdgcn_mfma_f32_16x16x32_bf16(a1, bfr[1][ct], acc[ct], 0, 0, 0);
    }
    ushort_t* gb = g + (size_t)t * 16 * HH;
#pragma unroll
    for (int ct = 0; ct < 4; ++ct)
#pragma unroll
      for (int r = 0; r < 4; ++r)
        gb[(lh * 4 + r) * HH + ct * 16 + li] = (ushort_t)f2bf(acc[ct][r]);
  }
}

// ---------------- aggregate: h2[r] = b + g[r] + sum g[src], + BN stats ----------------
// full wave per row; lane = (slot=lane>>3, colgroup c=lane&7).
// One dwordx4 instruction gathers 8 edges x 128B. Cross-slot shfl reduce.
#define ACC8(V)                                              \
  a0 += bflo((V).x); a1 += bfhi((V).x);                      \
  a2 += bflo((V).y); a3 += bfhi((V).y);                      \
  a4 += bflo((V).z); a5 += bfhi((V).z);                      \
  a6 += bflo((V).w); a7 += bfhi((V).w);

__global__ __launch_bounds__(256) void k_agg(
    const ushort_t* __restrict__ g, const int* __restrict__ rowstart,
    const int* __restrict__ deg, const int* __restrict__ srcl,
    const float* __restrict__ bias, float* __restrict__ h2,
    float* __restrict__ stats) {
  const int lane = threadIdx.x & 63;
  const int slot = lane >> 3;          // edge slot 0..7
  const int c    = lane & 7;           // column group: cols 8c..8c+7
  const int gw = (blockIdx.x * 256 + (int)threadIdx.x) >> 6;
  const int nw = (gridDim.x * 256) >> 6;
  const ushort_t* gc = g + c * 8;      // column offset within row
  const float4 b0 = *(const float4*)(bias + c * 8);
  const float4 b1 = *(const float4*)(bias + c * 8 + 4);

  float ps0 = 0.f, ps1 = 0.f, ps2 = 0.f, ps3 = 0.f;
  float ps4 = 0.f, ps5 = 0.f, ps6 = 0.f, ps7 = 0.f;
  float pq0 = 0.f, pq1 = 0.f, pq2 = 0.f, pq3 = 0.f;
  float pq4 = 0.f, pq5 = 0.f, pq6 = 0.f, pq7 = 0.f;

  for (int row = gw; row < NN; row += nw) {
    int s0 = rowstart[row];
    int d  = deg[row];
    float a0 = 0.f, a1 = 0.f, a2 = 0.f, a3 = 0.f;
    float a4 = 0.f, a5 = 0.f, a6 = 0.f, a7 = 0.f;

    int nfull = d >> 3;
    int k = 0;
    for (; k + 2 <= nfull; k += 2) {
      int ia = srcl[s0 + (k << 3) + slot];
      int ib = srcl[s0 + ((k + 1) << 3) + slot];
      uint4 va = *(const uint4*)(gc + (size_t)ia * HH);
      uint4 vb = *(const uint4*)(gc + (size_t)ib * HH);
      ACC8(va); ACC8(vb);
    }
    if (k < nfull) {
      int ia = srcl[s0 + (k << 3) + slot];
      uint4 va = *(const uint4*)(gc + (size_t)ia * HH);
      ACC8(va);
    }
    int rem = d & 7;
    if (slot < rem) {
      int ia = srcl[s0 + (nfull << 3) + slot];
      uint4 va = *(const uint4*)(gc + (size_t)ia * HH);
      ACC8(va);
    }

    // reduce across the 8 slots (offsets 8,16,32)
#pragma unroll
    for (int off = 8; off < 64; off <<= 1) {
      a0 += __shfl_xor(a0, off); a1 += __shfl_xor(a1, off);
      a2 += __shfl_xor(a2, off); a3 += __shfl_xor(a3, off);
      a4 += __shfl_xor(a4, off); a5 += __shfl_xor(a5, off);
      a6 += __shfl_xor(a6, off); a7 += __shfl_xor(a7, off);
    }

    if (slot == 0) {
      uint4 sv = *(const uint4*)(gc + (size_t)row * HH);   // self
      a0 += b0.x + bflo(sv.x); a1 += b0.y + bfhi(sv.x);
      a2 += b0.z + bflo(sv.y); a3 += b0.w + bfhi(sv.y);
      a4 += b1.x + bflo(sv.z); a5 += b1.y + bfhi(sv.z);
      a6 += b1.z + bflo(sv.w); a7 += b1.w + bfhi(sv.w);
      float4 o0; o0.x = a0; o0.y = a1; o0.z = a2; o0.w = a3;
      float4 o1; o1.x = a4; o1.y = a5; o1.z = a6; o1.w = a7;
      *(float4*)(h2 + (size_t)row * HH + c * 8)     = o0;
      *(float4*)(h2 + (size_t)row * HH + c * 8 + 4) = o1;
      ps0 += a0; ps1 += a1; ps2 += a2; ps3 += a3;
      ps4 += a4; ps5 += a5; ps6 += a6; ps7 += a7;
      pq0 += a0 * a0; pq1 += a1 * a1; pq2 += a2 * a2; pq3 += a3 * a3;
      pq4 += a4 * a4; pq5 += a5 * a5; pq6 += a6 * a6; pq7 += a7 * a7;
    }
  }

  if (slot == 0) {
    atomicAdd(&stats[c * 8 + 0], ps0); atomicAdd(&stats[c * 8 + 1], ps1);
    atomicAdd(&stats[c * 8 + 2], ps2); atomicAdd(&stats[c * 8 + 3], ps3);
    atomicAdd(&stats[c * 8 + 4], ps4); atomicAdd(&stats[c * 8 + 5], ps5);
    atomicAdd(&stats[c * 8 + 6], ps6); atomicAdd(&stats[c * 8 + 7], ps7);
    atomicAdd(&stats[HH + c * 8 + 0], pq0); atomicAdd(&stats[HH + c * 8 + 1], pq1);
    atomicAdd(&stats[HH + c * 8 + 2], pq2); atomicAdd(&stats[HH + c * 8 + 3], pq3);
    atomicAdd(&stats[HH + c * 8 + 4], pq4); atomicAdd(&stats[HH + c * 8 + 5], pq5);
    atomicAdd(&stats[HH + c * 8 + 6], pq6); atomicAdd(&stats[HH + c * 8 + 7], pq7);
  }
}

// ---------------- final: wsi = max0 + max1 ----------------
__global__ void k_wsi(const float* __restrict__ m0, const float* __restrict__ m1,
                      float* __restrict__ out) {
  int i = threadIdx.x;                                // 32 threads
  out[i] = m0[i] + m1[i];
}

extern "C" void kernel_launch(void* const* d_in, const int* in_sizes, int n_in,
                              void* d_out, int out_size, void* d_ws, size_t ws_size,
                              hipStream_t stream) {
  const float* x    = (const float*)d_in[0];
  const int*   ei   = (const int*)d_in[1];
  const int*   bat  = (const int*)d_in[2];
  const float* Wf   = (const float*)d_in[3];
  const float* bf   = (const float*)d_in[4];
  const float* g1   = (const float*)d_in[5];
  const float* be1  = (const float*)d_in[6];
  const float* Wl0  = (const float*)d_in[7];
  const float* bl0  = (const float*)d_in[8];
  const float* Wc   = (const float*)d_in[9];
  const float* bc   = (const float*)d_in[10];
  const float* g2   = (const float*)d_in[11];
  const float* be2  = (const float*)d_in[12];
  const float* Wl1  = (const float*)d_in[13];
  const float* bl1  = (const float*)d_in[14];

  float* out   = (float*)d_out;
  float* wsi   = out;                 // [8,4]
  float* npred = out + GG * TT;       // [N,4]

  float*    ws     = (float*)d_ws;
  float*    hbuf   = ws;                              // N*H fp32 (h1, then h2)
  ushort_t* fbf    = (ushort_t*)(hbuf + (size_t)NN * HH);  // N*H bf16
  ushort_t* gbf    = fbf + (size_t)NN * HH;           // N*H bf16
  float*    stats1 = (float*)(gbf + (size_t)NN * HH); // 256
  float*    stats2 = stats1 + 256;                    // 256
  float*    maxb   = stats2 + 256;                    // 64
  int*      deg      = (int*)(maxb + 64);             // N
  int*      rowstart = deg + NN;                      // N
  int*      cursor   = rowstart + NN;                 // N
  int*      bsum     = cursor + NN;                   // 128
  int*      bscan    = bsum + 128;                    // 128
  int*      srcl     = bscan + 128;                   // NE
  ushort_t* Wbf      = (ushort_t*)(srcl + NE);        // DF*HH
  ushort_t* Wbf2     = Wbf + DF * HH;                 // HH*HH

  hipMemsetAsync(deg, 0, NN * sizeof(int), stream);
  k_init<<<dim3(1), dim3(512), 0, stream>>>(stats1, maxb);
  k_prep<<<dim3(64), dim3(256), 0, stream>>>(Wf, Wbf, DF * HH);
  k_prep<<<dim3(16), dim3(256), 0, stream>>>(Wc, Wbf2, HH * HH);

  // CSR build
  k_count<<<dim3(1024), dim3(256), 0, stream>>>(ei, deg);
  k_scanA<<<dim3(NB_SCAN), dim3(256), 0, stream>>>(deg, rowstart, bsum);
  k_scanB<<<dim3(1), dim3(128), 0, stream>>>(bsum, bscan);
  k_scanC<<<dim3(NB_SCAN), dim3(256), 0, stream>>>(rowstart, bscan, cursor);
  k_fill<<<dim3(1024), dim3(256), 0, stream>>>(ei, cursor, srcl);

  // Layer 0
  k_gemm1_mfma<<<dim3(512), dim3(256), 0, stream>>>(x, Wbf, bf, hbuf, stats1);
  k_finalize_bn<<<dim3(1), dim3(64), 0, stream>>>(stats1, g1, be1, stats1 + 128);
  k_norm_np<1, 0><<<dim3(512), dim3(256), 0, stream>>>(
      hbuf, fbf, stats1 + 128, Wl0, bl0, bat, npred, maxb, (NN + 511) / 512);

  // Layer 1: g = f@Wc, then h2 = g + A.g + b (linearity of GIN)
  k_gemm2_mfma<<<dim3(512), dim3(256), 0, stream>>>(fbf, Wbf2, gbf);
  k_agg<<<dim3(2048), dim3(256), 0, stream>>>(gbf, rowstart, deg, srcl, bc, hbuf, stats2);
  k_finalize_bn<<<dim3(1), dim3(64), 0, stream>>>(stats2, g2, be2, stats2 + 128);
  k_norm_np<0, 1><<<dim3(512), dim3(256), 0, stream>>>(
      hbuf, fbf, stats2 + 128, Wl1, bl1, bat, npred, maxb + 32, (NN + 511) / 512);

  k_wsi<<<dim3(1), dim3(32), 0, stream>>>(maxb, maxb + 32, wsi);
}

// Round 7
// 575.989 us; speedup vs baseline: 3.5081x; 3.5081x over previous
//
#include <hip/hip_runtime.h>
#include <math.h>

#define NN 100000
#define NE 1600000
#define DF 256
#define HH 64
#define TT 4
#define GG 8
#define BN_EPS 1e-5f

#define SCAN_BLK 1024
#define NB_SCAN ((NN + SCAN_BLK - 1) / SCAN_BLK)   // 98

typedef __attribute__((ext_vector_type(8))) short short8v;
typedef __attribute__((ext_vector_type(4))) float f32x4;
typedef unsigned short ushort_t;
typedef unsigned int uint_t;

__device__ __forceinline__ void atomicMaxF(float* addr, float val) {
  if (val >= 0.f) atomicMax((int*)addr, __float_as_int(val));
  else            atomicMin((unsigned int*)addr, __float_as_uint(val));
}

// fp32 -> bf16 bits, round-to-nearest-even
__device__ __forceinline__ short f2bf(float f) {
  uint_t u = __float_as_uint(f);
  u += 0x7FFFu + ((u >> 16) & 1u);
  return (short)(u >> 16);
}

// ---------------- init: stats=0, max buffers=-inf ----------------
__global__ void k_init(float* __restrict__ stats, float* __restrict__ maxb) {
  int i = threadIdx.x;
  if (i < 512) stats[i] = 0.f;
  if (i < 64)  maxb[i]  = -INFINITY;
}

// ---------------- prep: fp32 -> bf16 bits ----------------
__global__ void k_prep(const float* __restrict__ W, ushort_t* __restrict__ Wbf, int n) {
  int i = blockIdx.x * 256 + threadIdx.x;
  if (i < n) Wbf[i] = (ushort_t)f2bf(W[i]);
}

// ---------------- GEMM1 (MFMA bf16): h1 = x @ W_first + b, + BN stats ----------------
__global__ __launch_bounds__(256, 2) void k_gemm1_mfma(
    const float* __restrict__ x, const ushort_t* __restrict__ Wbf,
    const float* __restrict__ b, float* __restrict__ h1,
    float* __restrict__ stats) {
  const int lane = threadIdx.x & 63;
  const int li = lane & 15;
  const int lh = lane >> 4;
  const int gw = (blockIdx.x * 256 + (int)threadIdx.x) >> 6;
  const int nw = (gridDim.x * 256) >> 6;

  short8v bf[8][4];
#pragma unroll
  for (int s = 0; s < 8; ++s)
#pragma unroll
    for (int ct = 0; ct < 4; ++ct)
#pragma unroll
      for (int e = 0; e < 8; ++e)
        bf[s][ct][e] = (short)Wbf[(32 * s + 8 * lh + e) * HH + ct * 16 + li];

  float bias[4];
#pragma unroll
  for (int ct = 0; ct < 4; ++ct) bias[ct] = b[ct * 16 + li];

  float ps[4] = {0.f, 0.f, 0.f, 0.f}, pss[4] = {0.f, 0.f, 0.f, 0.f};

  for (int t = gw; t < NN / 16; t += nw) {
    const float* xb = x + (size_t)(t * 16 + li) * DF + 8 * lh;
    f32x4 acc[4];
#pragma unroll
    for (int ct = 0; ct < 4; ++ct) acc[ct] = (f32x4){0.f, 0.f, 0.f, 0.f};

#pragma unroll
    for (int s = 0; s < 8; ++s) {
      float4 a0 = *(const float4*)(xb + 32 * s);
      float4 a1 = *(const float4*)(xb + 32 * s + 4);
      short8v af;
      af[0] = f2bf(a0.x); af[1] = f2bf(a0.y); af[2] = f2bf(a0.z); af[3] = f2bf(a0.w);
      af[4] = f2bf(a1.x); af[5] = f2bf(a1.y); af[6] = f2bf(a1.z); af[7] = f2bf(a1.w);
#pragma unroll
      for (int ct = 0; ct < 4; ++ct)
        acc[ct] = __builtin_amdgcn_mfma_f32_16x16x32_bf16(af, bf[s][ct], acc[ct], 0, 0, 0);
    }

    float* hb = h1 + (size_t)t * 16 * HH;
#pragma unroll
    for (int ct = 0; ct < 4; ++ct) {
#pragma unroll
      for (int r = 0; r < 4; ++r) {
        float h = acc[ct][r] + bias[ct];
        hb[(lh * 4 + r) * HH + ct * 16 + li] = h;
        ps[ct] += h; pss[ct] += h * h;
      }
    }
  }

#pragma unroll
  for (int ct = 0; ct < 4; ++ct) {
    ps[ct]  += __shfl_xor(ps[ct], 16);  ps[ct]  += __shfl_xor(ps[ct], 32);
    pss[ct] += __shfl_xor(pss[ct], 16); pss[ct] += __shfl_xor(pss[ct], 32);
  }
  if (lane < 16) {
#pragma unroll
    for (int ct = 0; ct < 4; ++ct) {
      atomicAdd(&stats[ct * 16 + lane], ps[ct]);
      atomicAdd(&stats[HH + ct * 16 + lane], pss[ct]);
    }
  }
}

// ---------------- BN finalize ----------------
__global__ void k_finalize_bn(const float* __restrict__ sums,
                              const float* __restrict__ gamma,
                              const float* __restrict__ beta,
                              float* __restrict__ ab) {
  int c = threadIdx.x;                                // 64 threads
  float mu  = sums[c] * (1.f / NN);
  float var = sums[HH + c] * (1.f / NN) - mu * mu;
  float a = gamma[c] * rsqrtf(var + BN_EPS);
  ab[c] = a;
  ab[HH + c] = beta[c] - mu * a;
}

// ---------------- normalize+ReLU + head (64->4) + graph max-pool ----------------
template <int WRITEF, int ADDOUT>
__global__ __launch_bounds__(256) void k_norm_np(
    const float* __restrict__ hin, ushort_t* __restrict__ fout,
    const float* __restrict__ ab, const float* __restrict__ Wlin,
    const float* __restrict__ blin, const int* __restrict__ batch,
    float* __restrict__ node_pred, float* __restrict__ maxbuf, int rpb) {
  __shared__ float lmax[GG * TT];
  if (threadIdx.x < GG * TT) lmax[threadIdx.x] = -INFINITY;
  __syncthreads();

  const int lane = threadIdx.x & 63;
  const int wid  = threadIdx.x >> 6;
  const float a  = ab[lane];
  const float b2 = ab[HH + lane];
  const float4 w = ((const float4*)Wlin)[lane];       // W[lane][0..3]
  const float4 bl = *(const float4*)blin;
  int r0 = blockIdx.x * rpb;
  int r1 = min(r0 + rpb, NN);

  for (int r = r0 + wid; r < r1; r += 4) {
    float h = hin[(size_t)r * HH + lane];
    float f = fmaxf(fmaf(a, h, b2), 0.f);
    if (WRITEF) fout[(size_t)r * HH + lane] = (ushort_t)f2bf(f);
    float p0 = f * w.x, p1 = f * w.y, p2 = f * w.z, p3 = f * w.w;
#pragma unroll
    for (int off = 32; off; off >>= 1) {
      p0 += __shfl_xor(p0, off);
      p1 += __shfl_xor(p1, off);
      p2 += __shfl_xor(p2, off);
      p3 += __shfl_xor(p3, off);
    }
    if (lane == 0) {
      float4 np;
      np.x = p0 + bl.x; np.y = p1 + bl.y; np.z = p2 + bl.z; np.w = p3 + bl.w;
      int g = batch[r];
      atomicMaxF(&lmax[g * TT + 0], np.x);
      atomicMaxF(&lmax[g * TT + 1], np.y);
      atomicMaxF(&lmax[g * TT + 2], np.z);
      atomicMaxF(&lmax[g * TT + 3], np.w);
      float4* op = (float4*)(node_pred + (size_t)r * TT);
      if (ADDOUT) {
        float4 o = *op;
        np.x += o.x; np.y += o.y; np.z += o.z; np.w += o.w;
      }
      *op = np;
    }
  }
  __syncthreads();
  if (threadIdx.x < GG * TT) atomicMaxF(&maxbuf[threadIdx.x], lmax[threadIdx.x]);
}

// ---------------- CSR build: histogram ----------------
__global__ __launch_bounds__(256) void k_count(const int* __restrict__ ei,
                                               int* __restrict__ deg) {
  int i = blockIdx.x * blockDim.x + threadIdx.x;
  int n = gridDim.x * blockDim.x;
  for (int e = i; e < NE; e += n) atomicAdd(&deg[ei[NE + e]], 1);
}

// ---------------- CSR build: 3-kernel exclusive scan ----------------
__global__ __launch_bounds__(256) void k_scanA(const int* __restrict__ deg,
                                               int* __restrict__ rowstart,
                                               int* __restrict__ bsum) {
  __shared__ int s[256];
  int t = threadIdx.x;
  int base = blockIdx.x * SCAN_BLK + t * 4;
  int d0 = 0, d1 = 0, d2 = 0, d3 = 0;
  if (base + 3 < NN) {
    int4 v = *(const int4*)(deg + base);
    d0 = v.x; d1 = v.y; d2 = v.z; d3 = v.w;
  } else {
    if (base + 0 < NN) d0 = deg[base + 0];
    if (base + 1 < NN) d1 = deg[base + 1];
    if (base + 2 < NN) d2 = deg[base + 2];
    if (base + 3 < NN) d3 = deg[base + 3];
  }
  int ts = d0 + d1 + d2 + d3;
  s[t] = ts;
  __syncthreads();
  for (int off = 1; off < 256; off <<= 1) {
    int v = (t >= off) ? s[t - off] : 0;
    __syncthreads();
    s[t] += v;
    __syncthreads();
  }
  int excl = s[t] - ts;                  // block-local exclusive prefix
  if (base + 0 < NN) rowstart[base + 0] = excl;  excl += d0;
  if (base + 1 < NN) rowstart[base + 1] = excl;  excl += d1;
  if (base + 2 < NN) rowstart[base + 2] = excl;  excl += d2;
  if (base + 3 < NN) rowstart[base + 3] = excl;
  if (t == 255) bsum[blockIdx.x] = s[255];
}

__global__ void k_scanB(const int* __restrict__ bsum, int* __restrict__ bscan) {
  __shared__ int s[128];
  int t = threadIdx.x;                   // 128 threads
  int v = (t < NB_SCAN) ? bsum[t] : 0;
  s[t] = v;
  __syncthreads();
  for (int off = 1; off < 128; off <<= 1) {
    int u = (t >= off) ? s[t - off] : 0;
    __syncthreads();
    s[t] += u;
    __syncthreads();
  }
  if (t < NB_SCAN) bscan[t] = s[t] - v;
}

__global__ __launch_bounds__(256) void k_scanC(int* __restrict__ rowstart,
                                               const int* __restrict__ bscan,
                                               int* __restrict__ cursor) {
  int off = bscan[blockIdx.x];
  int base = blockIdx.x * SCAN_BLK + threadIdx.x * 4;
#pragma unroll
  for (int j = 0; j < 4; ++j) {
    int i = base + j;
    if (i < NN) {
      int r = rowstart[i] + off;
      rowstart[i] = r;
      cursor[i] = r;
    }
  }
}

// ---------------- CSR build: fill src lists ----------------
__global__ __launch_bounds__(256) void k_fill(const int* __restrict__ ei,
                                              int* __restrict__ cursor,
                                              int* __restrict__ srcl) {
  int i = blockIdx.x * blockDim.x + threadIdx.x;
  int n = gridDim.x * blockDim.x;
  for (int e = i; e < NE; e += n) {
    int src = ei[e];
    int dst = ei[NE + e];
    int p = atomicAdd(&cursor[dst], 1);
    srcl[p] = src;
  }
}

// ---------------- GEMM2 (MFMA bf16): g = f @ W_conv (no bias), fp32 out ----------------
__global__ __launch_bounds__(256) void k_gemm2_mfma(
    const ushort_t* __restrict__ fbf, const ushort_t* __restrict__ Wbf2,
    float* __restrict__ g) {
  const int lane = threadIdx.x & 63;
  const int li = lane & 15;
  const int lh = lane >> 4;
  const int gw = (blockIdx.x * 256 + (int)threadIdx.x) >> 6;
  const int nw = (gridDim.x * 256) >> 6;

  short8v bfr[2][4];
#pragma unroll
  for (int s = 0; s < 2; ++s)
#pragma unroll
    for (int ct = 0; ct < 4; ++ct)
#pragma unroll
      for (int e = 0; e < 8; ++e)
        bfr[s][ct][e] = (short)Wbf2[(32 * s + 8 * lh + e) * HH + ct * 16 + li];

  for (int t = gw; t < NN / 16; t += nw) {
    const ushort_t* fb = fbf + (size_t)(t * 16 + li) * HH + 8 * lh;
    short8v a0 = *(const short8v*)(fb);
    short8v a1 = *(const short8v*)(fb + 32);
    f32x4 acc[4];
#pragma unroll
    for (int ct = 0; ct < 4; ++ct) {
      acc[ct] = (f32x4){0.f, 0.f, 0.f, 0.f};
      acc[ct] = __builtin_amdgcn_mfma_f32_16x16x32_bf16(a0, bfr[0][ct], acc[ct], 0, 0, 0);
      acc[ct] = __builtin_amdgcn_mfma_f32_16x16x32_bf16(a1, bfr[1][ct], acc[ct], 0, 0, 0);
    }
    float* gb = g + (size_t)t * 16 * HH;
#pragma unroll
    for (int ct = 0; ct < 4; ++ct)
#pragma unroll
      for (int r = 0; r < 4; ++r)
        gb[(lh * 4 + r) * HH + ct * 16 + li] = acc[ct][r];
  }
}

// ---------------- gather: h2[r] = b + g[r] + sum g[src], + BN stats ----------------
// R3 structure: block-contiguous rows (scalar-cache-friendly), wave per row,
// lane = column (4B fp32 -> 2 segments/instr). Inline-asm 8-load blocks force
// 8 gathers in flight (compiler refuses >1-2 from plain C: R4-R6 evidence).
__global__ __launch_bounds__(256) void k_gather(
    const float* __restrict__ g, const int* __restrict__ rowstart,
    const int* __restrict__ deg, const int* __restrict__ srcl,
    const float* __restrict__ bias, float* __restrict__ h2,
    float* __restrict__ stats, int rpb) {
  const int lane = threadIdx.x & 63;
  const int wid  = threadIdx.x >> 6;
  const float bc = bias[lane];
  const float* gl = g + lane;            // row r -> gl[r*HH]
  int r0 = blockIdx.x * rpb;
  int r1 = min(r0 + rpb, NN);
  float ps = 0.f, pss = 0.f;

  for (int row = r0 + wid; row < r1; row += 4) {
    int s0 = rowstart[row];
    int d  = deg[row];
    float acc = bc + gl[(size_t)row * HH];
    int e = 0;
    for (; e + 8 <= d; e += 8) {
      int i0 = srcl[s0 + e + 0]; int i1 = srcl[s0 + e + 1];
      int i2 = srcl[s0 + e + 2]; int i3 = srcl[s0 + e + 3];
      int i4 = srcl[s0 + e + 4]; int i5 = srcl[s0 + e + 5];
      int i6 = srcl[s0 + e + 6]; int i7 = srcl[s0 + e + 7];
      const float* p0 = gl + (size_t)i0 * HH;
      const float* p1 = gl + (size_t)i1 * HH;
      const float* p2 = gl + (size_t)i2 * HH;
      const float* p3 = gl + (size_t)i3 * HH;
      const float* p4 = gl + (size_t)i4 * HH;
      const float* p5 = gl + (size_t)i5 * HH;
      const float* p6 = gl + (size_t)i6 * HH;
      const float* p7 = gl + (size_t)i7 * HH;
      float v0, v1, v2, v3, v4, v5, v6, v7;
      asm volatile(
        "global_load_dword %0, %8, off\n\t"
        "global_load_dword %1, %9, off\n\t"
        "global_load_dword %2, %10, off\n\t"
        "global_load_dword %3, %11, off\n\t"
        "global_load_dword %4, %12, off\n\t"
        "global_load_dword %5, %13, off\n\t"
        "global_load_dword %6, %14, off\n\t"
        "global_load_dword %7, %15, off\n\t"
        "s_waitcnt vmcnt(0)"
        : "=&v"(v0), "=&v"(v1), "=&v"(v2), "=&v"(v3),
          "=&v"(v4), "=&v"(v5), "=&v"(v6), "=&v"(v7)
        : "v"(p0), "v"(p1), "v"(p2), "v"(p3),
          "v"(p4), "v"(p5), "v"(p6), "v"(p7)
        : "memory");
      acc += ((v0 + v1) + (v2 + v3)) + ((v4 + v5) + (v6 + v7));
    }
    for (; e < d; ++e) acc += gl[(size_t)srcl[s0 + e] * HH];
    h2[(size_t)row * HH + lane] = acc;
    ps += acc; pss += acc * acc;
  }
  atomicAdd(&stats[lane], ps);
  atomicAdd(&stats[HH + lane], pss);
}

// ---------------- final: wsi = max0 + max1 ----------------
__global__ void k_wsi(const float* __restrict__ m0, const float* __restrict__ m1,
                      float* __restrict__ out) {
  int i = threadIdx.x;                                // 32 threads
  out[i] = m0[i] + m1[i];
}

extern "C" void kernel_launch(void* const* d_in, const int* in_sizes, int n_in,
                              void* d_out, int out_size, void* d_ws, size_t ws_size,
                              hipStream_t stream) {
  const float* x    = (const float*)d_in[0];
  const int*   ei   = (const int*)d_in[1];
  const int*   bat  = (const int*)d_in[2];
  const float* Wf   = (const float*)d_in[3];
  const float* bf   = (const float*)d_in[4];
  const float* g1   = (const float*)d_in[5];
  const float* be1  = (const float*)d_in[6];
  const float* Wl0  = (const float*)d_in[7];
  const float* bl0  = (const float*)d_in[8];
  const float* Wc   = (const float*)d_in[9];
  const float* bc   = (const float*)d_in[10];
  const float* g2   = (const float*)d_in[11];
  const float* be2  = (const float*)d_in[12];
  const float* Wl1  = (const float*)d_in[13];
  const float* bl1  = (const float*)d_in[14];

  float* out   = (float*)d_out;
  float* wsi   = out;                 // [8,4]
  float* npred = out + GG * TT;       // [N,4]

  float*    ws     = (float*)d_ws;
  float*    hbuf   = ws;                              // N*H fp32 (h1, then h2)
  float*    gfp    = hbuf + (size_t)NN * HH;          // N*H fp32 (g = f@Wc)
  ushort_t* fbf    = (ushort_t*)(gfp + (size_t)NN * HH);   // N*H bf16
  float*    stats1 = (float*)(fbf + (size_t)NN * HH); // 256
  float*    stats2 = stats1 + 256;                    // 256
  float*    maxb   = stats2 + 256;                    // 64
  int*      deg      = (int*)(maxb + 64);             // N
  int*      rowstart = deg + NN;                      // N
  int*      cursor   = rowstart + NN;                 // N
  int*      bsum     = cursor + NN;                   // 128
  int*      bscan    = bsum + 128;                    // 128
  int*      srcl     = bscan + 128;                   // NE
  ushort_t* Wbf      = (ushort_t*)(srcl + NE);        // DF*HH
  ushort_t* Wbf2     = Wbf + DF * HH;                 // HH*HH

  hipMemsetAsync(deg, 0, NN * sizeof(int), stream);
  k_init<<<dim3(1), dim3(512), 0, stream>>>(stats1, maxb);
  k_prep<<<dim3(64), dim3(256), 0, stream>>>(Wf, Wbf, DF * HH);
  k_prep<<<dim3(16), dim3(256), 0, stream>>>(Wc, Wbf2, HH * HH);

  // CSR build
  k_count<<<dim3(1024), dim3(256), 0, stream>>>(ei, deg);
  k_scanA<<<dim3(NB_SCAN), dim3(256), 0, stream>>>(deg, rowstart, bsum);
  k_scanB<<<dim3(1), dim3(128), 0, stream>>>(bsum, bscan);
  k_scanC<<<dim3(NB_SCAN), dim3(256), 0, stream>>>(rowstart, bscan, cursor);
  k_fill<<<dim3(1024), dim3(256), 0, stream>>>(ei, cursor, srcl);

  // Layer 0
  k_gemm1_mfma<<<dim3(512), dim3(256), 0, stream>>>(x, Wbf, bf, hbuf, stats1);
  k_finalize_bn<<<dim3(1), dim3(64), 0, stream>>>(stats1, g1, be1, stats1 + 128);
  k_norm_np<1, 0><<<dim3(512), dim3(256), 0, stream>>>(
      hbuf, fbf, stats1 + 128, Wl0, bl0, bat, npred, maxb, (NN + 511) / 512);

  // Layer 1: g = f@Wc (MFMA), then h2 = b + g + A.g (linearity of GIN)
  k_gemm2_mfma<<<dim3(512), dim3(256), 0, stream>>>(fbf, Wbf2, gfp);
  {
    int rpb = 112;                            // contiguous rows per block
    int nb = (NN + rpb - 1) / rpb;            // 893
    k_gather<<<dim3(nb), dim3(256), 0, stream>>>(
        gfp, rowstart, deg, srcl, bc, hbuf, stats2, rpb);
  }
  k_finalize_bn<<<dim3(1), dim3(64), 0, stream>>>(stats2, g2, be2, stats2 + 128);
  k_norm_np<0, 1><<<dim3(512), dim3(256), 0, stream>>>(
      hbuf, fbf, stats2 + 128, Wl1, bl1, bat, npred, maxb + 32, (NN + 511) / 512);

  k_wsi<<<dim3(1), dim3(32), 0, stream>>>(maxb, maxb + 32, wsi);
}